// Round 6
// baseline (160.342 us; speedup 1.0000x reference)
//
#include <hip/hip_runtime.h>

#define DIM 1024
#define NHEADS 16
#define HDIM 64
#define BATCH 2
#define SEQ 2048
#define MTOT (BATCH*SEQ)
// 1/sqrt(64) * log2(e), folded into Q so softmax uses exp2
#define QSCALE 0.18033688011112042f
#define XN ((size_t)MTOT*DIM)
#define WN ((size_t)DIM*DIM)

typedef __attribute__((ext_vector_type(8))) short short8;
typedef __attribute__((ext_vector_type(4))) float f32x4;
typedef __attribute__((ext_vector_type(16))) float f32x16;
typedef __attribute__((ext_vector_type(2))) int int2v;

static __device__ __forceinline__ unsigned short bf16rne(float f) {
    unsigned u = __builtin_bit_cast(unsigned, f);
    return (unsigned short)((u + 0x7fffu + ((u >> 16) & 1u)) >> 16);
}

// async global->LDS, 16B per lane; LDS dest must be wave-uniform (HW adds lane*16).
static __device__ __forceinline__ void gld16(const void* g, void* l) {
    __builtin_amdgcn_global_load_lds((const __attribute__((address_space(1))) void*)g,
                                     (__attribute__((address_space(3))) void*)l, 16, 0, 0);
}

static __device__ __forceinline__ f32x16 mfma32(short8 a, short8 b, f32x16 c) {
    return __builtin_amdgcn_mfma_f32_32x32x16_bf16(a, b, c, 0, 0, 0);
}

// ---------------- fused f32 -> bf16 convert of x + 4 weights ----------------
__global__ __launch_bounds__(256)
void prep(const float* __restrict__ x, const float* __restrict__ wq, const float* __restrict__ wk,
          const float* __restrict__ wv, const float* __restrict__ wo, unsigned short* __restrict__ dst)
{
    const size_t i = ((size_t)blockIdx.x*256 + threadIdx.x)*8;
    const float* s; size_t o;
    if (i < XN)           { s = x;  o = i; }
    else if (i < XN+WN)   { s = wq; o = i - XN; }
    else if (i < XN+2*WN) { s = wk; o = i - XN - WN; }
    else if (i < XN+3*WN) { s = wv; o = i - XN - 2*WN; }
    else                  { s = wo; o = i - XN - 3*WN; }
    float4 a = *(const float4*)(s + o);
    float4 b = *(const float4*)(s + o + 4);
    uint4 w;
    w.x = (unsigned)bf16rne(a.x) | ((unsigned)bf16rne(a.y) << 16);
    w.y = (unsigned)bf16rne(a.z) | ((unsigned)bf16rne(a.w) << 16);
    w.z = (unsigned)bf16rne(b.x) | ((unsigned)bf16rne(b.y) << 16);
    w.w = (unsigned)bf16rne(b.z) | ((unsigned)bf16rne(b.w) << 16);
    *(uint4*)&dst[i] = w;
}

// ---------------- fused QKV bf16 GEMM, m97-structure, XCD-swizzled ----------------
// 128x128 tile, BK=32, 256 thr (4 waves 2x2), wave tile 64x64.
// widx==2 (V) writes DIRECTLY TRANSPOSED to Vt[b,h,d,s] (vectorized 8B stores):
// the transpose kernel is fused away.
__global__ __launch_bounds__(256)
void gemm_qkv(const unsigned short* __restrict__ A,
              const unsigned short* __restrict__ W0, const unsigned short* __restrict__ W1,
              const unsigned short* __restrict__ W2,
              const float* __restrict__ b0, const float* __restrict__ b1, const float* __restrict__ b2,
              unsigned short* __restrict__ o0, unsigned short* __restrict__ o1, unsigned short* __restrict__ o2)
{
    __shared__ __align__(16) unsigned short As[2][4096];
    __shared__ __align__(16) unsigned short Bs[2][4096];
    const int t = threadIdx.x, wid = t >> 6, lane = t & 63;
    const int lr = lane & 15, lg = lane >> 4;
    // XCD swizzle: 768 blocks, XCD c gets 4 consecutive m-panels (1 MB A) + B (6 MB)
    const int bid = blockIdx.y * 24 + blockIdx.x;
    const int swz = (bid & 7) * 96 + (bid >> 3);
    const int sx = swz % 24, sy = swz / 24;
    const int widx = sx >> 3;
    const int n0 = (sx & 7) << 7;
    const int m0 = sy << 7;
    const unsigned short* W = widx == 0 ? W0 : (widx == 1 ? W1 : W2);
    const float* bias        = widx == 0 ? b0 : (widx == 1 ? b1 : b2);
    const float scale        = widx == 0 ? QSCALE : 1.0f;
    unsigned short* out      = widx == 0 ? o0 : (widx == 1 ? o1 : o2);

    const int wm = wid >> 1, wn = wid & 1;
    const int f0 = 2*wid, f1 = f0 + 1;
    const unsigned short* Ag0 = A + (size_t)(m0 + f0*16 + lr)*DIM + lg*8;
    const unsigned short* Ag1 = A + (size_t)(m0 + f1*16 + lr)*DIM + lg*8;
    const unsigned short* Bg0 = W + (size_t)(n0 + f0*16 + lr)*DIM + lg*8;
    const unsigned short* Bg1 = W + (size_t)(n0 + f1*16 + lr)*DIM + lg*8;

    f32x4 acc[4][4] = {};

    gld16(Ag0, &As[0][f0*512]); gld16(Ag1, &As[0][f1*512]);
    gld16(Bg0, &Bs[0][f0*512]); gld16(Bg1, &Bs[0][f1*512]);

    for (int it = 0; it < DIM/32; ++it) {
        __syncthreads();   // drains vmcnt: buf[it&1] ready; prev compute done
        {   // branchless prefetch (wraps on last iter into unused buffer)
            const int nbf = (it+1)&1; const int ko = ((it+1)&31)*32;
            gld16(Ag0 + ko, &As[nbf][f0*512]); gld16(Ag1 + ko, &As[nbf][f1*512]);
            gld16(Bg0 + ko, &Bs[nbf][f0*512]); gld16(Bg1 + ko, &Bs[nbf][f1*512]);
        }
        const int cb = it & 1;
        short8 af[4], bf[4];
        #pragma unroll
        for (int i = 0; i < 4; ++i) af[i] = *(const short8*)&As[cb][(wm*4+i)*512 + lane*8];
        #pragma unroll
        for (int i = 0; i < 4; ++i) bf[i] = *(const short8*)&Bs[cb][(wn*4+i)*512 + lane*8];
        __builtin_amdgcn_s_setprio(1);
        #pragma unroll
        for (int mb = 0; mb < 4; ++mb)
            #pragma unroll
            for (int nb = 0; nb < 4; ++nb)
                acc[mb][nb] = __builtin_amdgcn_mfma_f32_16x16x32_bf16(af[mb], bf[nb], acc[mb][nb], 0, 0, 0);
        __builtin_amdgcn_s_setprio(0);
    }

    if (widx == 2) {
        // V: write transposed Vt[(b*16+h)*64 + d][s], 4 consecutive s per lane -> 8B stores
        const int bb  = m0 >> 11;                 // batch
        const int sb  = (m0 & (SEQ-1)) + wm*64;   // s base of this wave
        #pragma unroll
        for (int nb = 0; nb < 4; ++nb) {
            const int col = n0 + wn*64 + nb*16 + lr;
            const int hh = col >> 6, dd = col & 63;
            const float bv = bias[col];
            unsigned short* vt = out + ((size_t)(bb*NHEADS + hh)*HDIM + dd)*SEQ;
            #pragma unroll
            for (int mb = 0; mb < 4; ++mb) {
                const int srow = sb + mb*16 + lg*4;
                unsigned w0 = (unsigned)bf16rne(acc[mb][nb][0]+bv) | ((unsigned)bf16rne(acc[mb][nb][1]+bv) << 16);
                unsigned w1 = (unsigned)bf16rne(acc[mb][nb][2]+bv) | ((unsigned)bf16rne(acc[mb][nb][3]+bv) << 16);
                *(uint2*)&vt[srow] = make_uint2(w0, w1);
            }
        }
    } else {
        #pragma unroll
        for (int nb = 0; nb < 4; ++nb) {
            const int col = n0 + wn*64 + nb*16 + lr;
            const float bv = bias[col];
            #pragma unroll
            for (int mb = 0; mb < 4; ++mb) {
                #pragma unroll
                for (int j = 0; j < 4; ++j) {
                    const int row = m0 + wm*64 + mb*16 + lg*4 + j;
                    out[(size_t)row*DIM + col] = bf16rne((acc[mb][nb][j] + bv) * scale);
                }
            }
        }
    }
}

// ---------------- O-projection GEMM: 64x128 tile -> 512 blocks (2/CU), f32 out ----------------
__global__ __launch_bounds__(256)
void gemm_o(const unsigned short* __restrict__ A, const unsigned short* __restrict__ W,
            const float* __restrict__ bias, float* __restrict__ fo)
{
    __shared__ __align__(16) unsigned short As[2][2048];   // 4 frags
    __shared__ __align__(16) unsigned short Bs[2][4096];   // 8 frags
    const int t = threadIdx.x, wid = t >> 6, lane = t & 63;
    const int lr = lane & 15, lg = lane >> 4;
    const int bid = blockIdx.y * 8 + blockIdx.x;           // grid (8, 64)
    const int swz = (bid & 7) * 64 + (bid >> 3);
    const int n0 = (swz & 7) << 7;
    const int m0 = (swz >> 3) << 6;
    const int wm = wid >> 1, wn = wid & 1;

    const int fa = wid;
    const int g0 = 2*wid, g1 = g0 + 1;
    const unsigned short* Ag  = A + (size_t)(m0 + fa*16 + lr)*DIM + lg*8;
    const unsigned short* Bg0 = W + (size_t)(n0 + g0*16 + lr)*DIM + lg*8;
    const unsigned short* Bg1 = W + (size_t)(n0 + g1*16 + lr)*DIM + lg*8;

    f32x4 acc[2][4] = {};

    gld16(Ag, &As[0][fa*512]);
    gld16(Bg0, &Bs[0][g0*512]); gld16(Bg1, &Bs[0][g1*512]);

    for (int it = 0; it < DIM/32; ++it) {
        __syncthreads();
        {
            const int nbf = (it+1)&1; const int ko = ((it+1)&31)*32;
            gld16(Ag + ko, &As[nbf][fa*512]);
            gld16(Bg0 + ko, &Bs[nbf][g0*512]); gld16(Bg1 + ko, &Bs[nbf][g1*512]);
        }
        const int cb = it & 1;
        short8 af[2], bf[4];
        #pragma unroll
        for (int i = 0; i < 2; ++i) af[i] = *(const short8*)&As[cb][(wm*2+i)*512 + lane*8];
        #pragma unroll
        for (int i = 0; i < 4; ++i) bf[i] = *(const short8*)&Bs[cb][(wn*4+i)*512 + lane*8];
        __builtin_amdgcn_s_setprio(1);
        #pragma unroll
        for (int mb = 0; mb < 2; ++mb)
            #pragma unroll
            for (int nb = 0; nb < 4; ++nb)
                acc[mb][nb] = __builtin_amdgcn_mfma_f32_16x16x32_bf16(af[mb], bf[nb], acc[mb][nb], 0, 0, 0);
        __builtin_amdgcn_s_setprio(0);
    }

    #pragma unroll
    for (int nb = 0; nb < 4; ++nb) {
        const int col = n0 + wn*64 + nb*16 + lr;
        const float bv = bias[col];
        #pragma unroll
        for (int mb = 0; mb < 2; ++mb) {
            #pragma unroll
            for (int j = 0; j < 4; ++j) {
                const int row = m0 + wm*32 + mb*16 + lg*4 + j;
                fo[(size_t)row*DIM + col] = acc[mb][nb][j] + bv;
            }
        }
    }
}

// ---------------- MFMA flash attention, 2-tile pipelined (T15-style) ----------------
// 256 thr (4 waves), block = 128 q rows of one (b,h); wave = 32 q rows.
// 4-buffer LDS rotation (64 KB), one barrier per TWO k-tiles. Within a window:
// QK(t0) -> sm(t0) -> QK(t1) -> PV(t0) -> sm(t1) -> PV(t1); QK(t1) can overlap
// sm(t0), PV(t0) overlaps sm(t1) (independent pipes, no deps).
struct PA { short8 p[4]; };

static __device__ __forceinline__ PA softmax_pack(const f32x16& s0, const f32x16& s1, float& lsum) {
    float rsum = 0.f;
    unsigned pw0[4][2], pw1[4][2];
    #pragma unroll
    for (int r1 = 0; r1 < 4; ++r1)
        #pragma unroll
        for (int tt = 0; tt < 2; ++tt) {
            float pa_ = __builtin_amdgcn_exp2f(s0[4*r1+2*tt]);
            float pb_ = __builtin_amdgcn_exp2f(s0[4*r1+2*tt+1]);
            float pc_ = __builtin_amdgcn_exp2f(s1[4*r1+2*tt]);
            float pd_ = __builtin_amdgcn_exp2f(s1[4*r1+2*tt+1]);
            rsum += (pa_ + pb_) + (pc_ + pd_);
            asm("v_cvt_pk_bf16_f32 %0, %1, %2" : "=v"(pw0[r1][tt]) : "v"(pa_), "v"(pb_));
            asm("v_cvt_pk_bf16_f32 %0, %1, %2" : "=v"(pw1[r1][tt]) : "v"(pc_), "v"(pd_));
        }
    rsum += __shfl_xor(rsum, 32);
    lsum += rsum;
    PA r;
    #pragma unroll
    for (int ss = 0; ss < 4; ++ss) {
        union { short8 s8; unsigned u[4]; } pu;
        #pragma unroll
        for (int tt = 0; tt < 2; ++tt) {
            const unsigned a = (ss >> 1) ? pw1[2*(ss&1)][tt]   : pw0[2*(ss&1)][tt];
            const unsigned b = (ss >> 1) ? pw1[2*(ss&1)+1][tt] : pw0[2*(ss&1)+1][tt];
            int2v sw = __builtin_amdgcn_permlane32_swap((int)a, (int)b, false, false);
            pu.u[tt]     = (unsigned)sw[0];
            pu.u[2 + tt] = (unsigned)sw[1];
        }
        r.p[ss] = pu.s8;
    }
    return r;
}

__global__ __launch_bounds__(256)
void attn_mfma2(const unsigned short* __restrict__ Q, const unsigned short* __restrict__ Kg,
                const unsigned short* __restrict__ Vt, unsigned short* __restrict__ O)
{
    __shared__ __align__(16) unsigned short Ks[4][4096];
    __shared__ __align__(16) unsigned short Vs[4][4096];
    const int t = threadIdx.x, wid = t >> 6, lane = t & 63;
    const int l31 = lane & 31, h = lane >> 5;
    // grid (16, 32) = 512 blocks; swizzle: XCD c gets heads 4c..4c+3
    const int bid = blockIdx.y * 16 + blockIdx.x;
    const int swz = (bid & 7) * 64 + (bid >> 3);
    const int qt = swz & 15, bh = swz >> 4;
    const int b = bh >> 4, hh = bh & 15;
    const size_t qkbase = (size_t)b*SEQ*DIM + (size_t)hh*HDIM;
    const unsigned short* Qb = Q + qkbase;
    const unsigned short* Kb = Kg + qkbase;
    const unsigned short* Vb = Vt + (size_t)bh*HDIM*SEQ;
    unsigned short*       Ob = O + qkbase;
    const int q0 = qt*128 + wid*32;

    short8 qf[4];   // Q as B-operand: lane holds Q[q0+l31][ds*16 + h*8 + e]
    #pragma unroll
    for (int ds = 0; ds < 4; ++ds)
        qf[ds] = *(const short8*)&Qb[(size_t)(q0 + l31)*DIM + ds*16 + h*8];

    const int f0 = 2*wid, f1 = f0 + 1;
    const unsigned short* Kg0 = &Kb[(size_t)((f0>>2)*32 + l31)*DIM + (f0&3)*16 + h*8];
    const unsigned short* Kg1 = &Kb[(size_t)((f1>>2)*32 + l31)*DIM + (f1&3)*16 + h*8];
    const unsigned short* Vg0 = &Vb[(size_t)((f0>>2)*32 + l31)*SEQ + (f0&3)*16 + h*8];
    const unsigned short* Vg1 = &Vb[(size_t)((f1>>2)*32 + l31)*SEQ + (f1&3)*16 + h*8];

    auto stage = [&](int tn) {
        const size_t koK = (size_t)tn * 64 * DIM;
        const size_t koV = (size_t)tn * 64;
        const int bb = tn & 3;
        gld16(Kg0 + koK, &Ks[bb][f0*512]); gld16(Kg1 + koK, &Ks[bb][f1*512]);
        gld16(Vg0 + koV, &Vs[bb][f0*512]); gld16(Vg1 + koV, &Vs[bb][f1*512]);
    };

    f32x16 ctx0 = {}, ctx1 = {};
    float lsum = 0.0f;

    stage(0); stage(1);

    for (int w = 0; w < SEQ/128; ++w) {
        const int t0 = 2*w;
        const int ba = t0 & 3, bb2 = (t0+1) & 3;
        __syncthreads();   // prev window's reads done; this window's bufs landed
        if (w + 1 < SEQ/128) { stage(t0+2); stage(t0+3); }

        // QK(t0)
        f32x16 s0a = {}, s1a = {};
        __builtin_amdgcn_s_setprio(1);
        #pragma unroll
        for (int ds = 0; ds < 4; ++ds) {
            short8 kf0 = *(const short8*)&Ks[ba][ds*512 + lane*8];
            short8 kf1 = *(const short8*)&Ks[ba][(4+ds)*512 + lane*8];
            s0a = mfma32(kf0, qf[ds], s0a);
            s1a = mfma32(kf1, qf[ds], s1a);
        }
        __builtin_amdgcn_s_setprio(0);

        PA pa = softmax_pack(s0a, s1a, lsum);

        // QK(t1) -- independent of sm(t0)/PV(t0); scheduler overlaps
        f32x16 s0b = {}, s1b = {};
        __builtin_amdgcn_s_setprio(1);
        #pragma unroll
        for (int ds = 0; ds < 4; ++ds) {
            short8 kf0 = *(const short8*)&Ks[bb2][ds*512 + lane*8];
            short8 kf1 = *(const short8*)&Ks[bb2][(4+ds)*512 + lane*8];
            s0b = mfma32(kf0, qf[ds], s0b);
            s1b = mfma32(kf1, qf[ds], s1b);
        }
        // PV(t0) -- MFMA pipe busy while sm(t1) VALU runs after
        #pragma unroll
        for (int ss = 0; ss < 4; ++ss) {
            short8 vf0 = *(const short8*)&Vs[ba][ss*512 + lane*8];
            short8 vf1 = *(const short8*)&Vs[ba][(4+ss)*512 + lane*8];
            ctx0 = mfma32(pa.p[ss], vf0, ctx0);
            ctx1 = mfma32(pa.p[ss], vf1, ctx1);
        }
        __builtin_amdgcn_s_setprio(0);

        PA pb = softmax_pack(s0b, s1b, lsum);

        // PV(t1)
        __builtin_amdgcn_s_setprio(1);
        #pragma unroll
        for (int ss = 0; ss < 4; ++ss) {
            short8 vf0 = *(const short8*)&Vs[bb2][ss*512 + lane*8];
            short8 vf1 = *(const short8*)&Vs[bb2][(4+ss)*512 + lane*8];
            ctx0 = mfma32(pb.p[ss], vf0, ctx0);
            ctx1 = mfma32(pb.p[ss], vf1, ctx1);
        }
        __builtin_amdgcn_s_setprio(0);
    }

    const float linv = 1.0f / lsum;
    #pragma unroll
    for (int r = 0; r < 16; ++r) {
        const int qrow = (r&3) + 8*(r>>2) + 4*h;
        const float nm = __shfl(linv, qrow);
        unsigned short* p = &Ob[(size_t)(q0 + qrow)*DIM + l31];
        p[0]  = bf16rne(ctx0[r] * nm);
        p[32] = bf16rne(ctx1[r] * nm);
    }
}

extern "C" void kernel_launch(void* const* d_in, const int* in_sizes, int n_in,
                              void* d_out, int out_size, void* d_ws, size_t ws_size,
                              hipStream_t stream) {
    const float* x  = (const float*)d_in[0];
    const float* wq = (const float*)d_in[1];
    const float* bq = (const float*)d_in[2];
    const float* wk = (const float*)d_in[3];
    const float* bk = (const float*)d_in[4];
    const float* wv = (const float*)d_in[5];
    const float* bv = (const float*)d_in[6];
    const float* wo = (const float*)d_in[7];
    const float* bo = (const float*)d_in[8];
    float* out = (float*)d_out;

    // ws (ushort): Xb 4M | Wq 1M | Wk 1M | Wv 1M | Wo 1M | Qb 4M | Kb 4M | Cb 4M | Vtb 4M = 48 MB
    unsigned short* Xb  = (unsigned short*)d_ws;
    unsigned short* Wqb = Xb  + XN;
    unsigned short* Wkb = Wqb + WN;
    unsigned short* Wvb = Wkb + WN;
    unsigned short* Wob = Wvb + WN;
    unsigned short* Qb  = Wob + WN;
    unsigned short* Kb  = Qb  + XN;
    unsigned short* Cb  = Kb  + XN;   // attn output (slot formerly raw V)
    unsigned short* Vtb = Cb  + XN;

    prep<<<4096, 256, 0, stream>>>(x, wq, wk, wv, wo, Xb);

    // V written directly transposed -> no transpose kernel
    gemm_qkv<<<dim3(24, 32), 256, 0, stream>>>(Xb, Wqb, Wkb, Wvb, bq, bk, bv, Qb, Kb, Vtb);

    attn_mfma2<<<dim3(SEQ/128, BATCH*NHEADS), 256, 0, stream>>>(Qb, Kb, Vtb, Cb);

    gemm_o<<<dim3(8, 64), 256, 0, stream>>>(Cb, Wob, bo, out);
}

// Round 7
// 157.797 us; speedup vs baseline: 1.0161x; 1.0161x over previous
//
#include <hip/hip_runtime.h>

#define DIM 1024
#define NHEADS 16
#define HDIM 64
#define BATCH 2
#define SEQ 2048
#define MTOT (BATCH*SEQ)
// 1/sqrt(64) * log2(e), folded into Q so softmax uses exp2
#define QSCALE 0.18033688011112042f
#define XN ((size_t)MTOT*DIM)
#define WN ((size_t)DIM*DIM)
// Vt row stride: 2208*2B = 4416B = 17.25*256B -> d-rows spread across all 16 L2
// channels (2048*2B = 4096B aliased every row onto ONE channel: 16-way serialization)
#define VSTR 2208

typedef __attribute__((ext_vector_type(8))) short short8;
typedef __attribute__((ext_vector_type(4))) float f32x4;
typedef __attribute__((ext_vector_type(16))) float f32x16;
typedef __attribute__((ext_vector_type(2))) int int2v;

static __device__ __forceinline__ unsigned short bf16rne(float f) {
    unsigned u = __builtin_bit_cast(unsigned, f);
    return (unsigned short)((u + 0x7fffu + ((u >> 16) & 1u)) >> 16);
}

// async global->LDS, 16B per lane; LDS dest must be wave-uniform (HW adds lane*16).
static __device__ __forceinline__ void gld16(const void* g, void* l) {
    __builtin_amdgcn_global_load_lds((const __attribute__((address_space(1))) void*)g,
                                     (__attribute__((address_space(3))) void*)l, 16, 0, 0);
}

static __device__ __forceinline__ f32x16 mfma32(short8 a, short8 b, f32x16 c) {
    return __builtin_amdgcn_mfma_f32_32x32x16_bf16(a, b, c, 0, 0, 0);
}

// ---------------- fused f32 -> bf16 convert of x + 4 weights ----------------
__global__ __launch_bounds__(256)
void prep(const float* __restrict__ x, const float* __restrict__ wq, const float* __restrict__ wk,
          const float* __restrict__ wv, const float* __restrict__ wo, unsigned short* __restrict__ dst)
{
    const size_t i = ((size_t)blockIdx.x*256 + threadIdx.x)*8;
    const float* s; size_t o;
    if (i < XN)           { s = x;  o = i; }
    else if (i < XN+WN)   { s = wq; o = i - XN; }
    else if (i < XN+2*WN) { s = wk; o = i - XN - WN; }
    else if (i < XN+3*WN) { s = wv; o = i - XN - 2*WN; }
    else                  { s = wo; o = i - XN - 3*WN; }
    float4 a = *(const float4*)(s + o);
    float4 b = *(const float4*)(s + o + 4);
    uint4 w;
    w.x = (unsigned)bf16rne(a.x) | ((unsigned)bf16rne(a.y) << 16);
    w.y = (unsigned)bf16rne(a.z) | ((unsigned)bf16rne(a.w) << 16);
    w.z = (unsigned)bf16rne(b.x) | ((unsigned)bf16rne(b.y) << 16);
    w.w = (unsigned)bf16rne(b.z) | ((unsigned)bf16rne(b.w) << 16);
    *(uint4*)&dst[i] = w;
}

// ---------------- fused QKV bf16 GEMM, m97-structure, XCD-swizzled ----------------
// 128x128 tile, BK=32, 256 thr (4 waves 2x2), wave tile 64x64.
// widx==2 (V) writes DIRECTLY TRANSPOSED to Vt[b,h,d,s] (8B stores, VSTR-padded
// rows so the 16 rows/instr spread across L2 channels).
__global__ __launch_bounds__(256)
void gemm_qkv(const unsigned short* __restrict__ A,
              const unsigned short* __restrict__ W0, const unsigned short* __restrict__ W1,
              const unsigned short* __restrict__ W2,
              const float* __restrict__ b0, const float* __restrict__ b1, const float* __restrict__ b2,
              unsigned short* __restrict__ o0, unsigned short* __restrict__ o1, unsigned short* __restrict__ o2)
{
    __shared__ __align__(16) unsigned short As[2][4096];
    __shared__ __align__(16) unsigned short Bs[2][4096];
    const int t = threadIdx.x, wid = t >> 6, lane = t & 63;
    const int lr = lane & 15, lg = lane >> 4;
    // XCD swizzle: 768 blocks, XCD c gets 4 consecutive m-panels (1 MB A) + B (6 MB)
    const int bid = blockIdx.y * 24 + blockIdx.x;
    const int swz = (bid & 7) * 96 + (bid >> 3);
    const int sx = swz % 24, sy = swz / 24;
    const int widx = sx >> 3;
    const int n0 = (sx & 7) << 7;
    const int m0 = sy << 7;
    const unsigned short* W = widx == 0 ? W0 : (widx == 1 ? W1 : W2);
    const float* bias        = widx == 0 ? b0 : (widx == 1 ? b1 : b2);
    const float scale        = widx == 0 ? QSCALE : 1.0f;
    unsigned short* out      = widx == 0 ? o0 : (widx == 1 ? o1 : o2);

    const int wm = wid >> 1, wn = wid & 1;
    const int f0 = 2*wid, f1 = f0 + 1;
    const unsigned short* Ag0 = A + (size_t)(m0 + f0*16 + lr)*DIM + lg*8;
    const unsigned short* Ag1 = A + (size_t)(m0 + f1*16 + lr)*DIM + lg*8;
    const unsigned short* Bg0 = W + (size_t)(n0 + f0*16 + lr)*DIM + lg*8;
    const unsigned short* Bg1 = W + (size_t)(n0 + f1*16 + lr)*DIM + lg*8;

    f32x4 acc[4][4] = {};

    gld16(Ag0, &As[0][f0*512]); gld16(Ag1, &As[0][f1*512]);
    gld16(Bg0, &Bs[0][f0*512]); gld16(Bg1, &Bs[0][f1*512]);

    for (int it = 0; it < DIM/32; ++it) {
        __syncthreads();   // drains vmcnt: buf[it&1] ready; prev compute done
        {   // branchless prefetch (wraps on last iter into unused buffer)
            const int nbf = (it+1)&1; const int ko = ((it+1)&31)*32;
            gld16(Ag0 + ko, &As[nbf][f0*512]); gld16(Ag1 + ko, &As[nbf][f1*512]);
            gld16(Bg0 + ko, &Bs[nbf][f0*512]); gld16(Bg1 + ko, &Bs[nbf][f1*512]);
        }
        const int cb = it & 1;
        short8 af[4], bf[4];
        #pragma unroll
        for (int i = 0; i < 4; ++i) af[i] = *(const short8*)&As[cb][(wm*4+i)*512 + lane*8];
        #pragma unroll
        for (int i = 0; i < 4; ++i) bf[i] = *(const short8*)&Bs[cb][(wn*4+i)*512 + lane*8];
        __builtin_amdgcn_s_setprio(1);
        #pragma unroll
        for (int mb = 0; mb < 4; ++mb)
            #pragma unroll
            for (int nb = 0; nb < 4; ++nb)
                acc[mb][nb] = __builtin_amdgcn_mfma_f32_16x16x32_bf16(af[mb], bf[nb], acc[mb][nb], 0, 0, 0);
        __builtin_amdgcn_s_setprio(0);
    }

    if (widx == 2) {
        // V: write transposed Vt[(b*16+h)*64 + d][s] with VSTR-padded rows
        const int bb  = m0 >> 11;                 // batch
        const int sb  = (m0 & (SEQ-1)) + wm*64;   // s base of this wave
        #pragma unroll
        for (int nb = 0; nb < 4; ++nb) {
            const int col = n0 + wn*64 + nb*16 + lr;
            const int hh = col >> 6, dd = col & 63;
            const float bv = bias[col];
            unsigned short* vt = out + (size_t)((bb*NHEADS + hh)*HDIM + dd)*VSTR;
            #pragma unroll
            for (int mb = 0; mb < 4; ++mb) {
                const int srow = sb + mb*16 + lg*4;
                unsigned w0 = (unsigned)bf16rne(acc[mb][nb][0]+bv) | ((unsigned)bf16rne(acc[mb][nb][1]+bv) << 16);
                unsigned w1 = (unsigned)bf16rne(acc[mb][nb][2]+bv) | ((unsigned)bf16rne(acc[mb][nb][3]+bv) << 16);
                *(uint2*)&vt[srow] = make_uint2(w0, w1);
            }
        }
    } else {
        #pragma unroll
        for (int nb = 0; nb < 4; ++nb) {
            const int col = n0 + wn*64 + nb*16 + lr;
            const float bv = bias[col];
            #pragma unroll
            for (int mb = 0; mb < 4; ++mb) {
                #pragma unroll
                for (int j = 0; j < 4; ++j) {
                    const int row = m0 + wm*64 + mb*16 + lg*4 + j;
                    out[(size_t)row*DIM + col] = bf16rne((acc[mb][nb][j] + bv) * scale);
                }
            }
        }
    }
}

// ---------------- O-projection GEMM: 64x128 tile -> 512 blocks (2/CU), f32 out ----------------
__global__ __launch_bounds__(256)
void gemm_o(const unsigned short* __restrict__ A, const unsigned short* __restrict__ W,
            const float* __restrict__ bias, float* __restrict__ fo)
{
    __shared__ __align__(16) unsigned short As[2][2048];   // 4 frags
    __shared__ __align__(16) unsigned short Bs[2][4096];   // 8 frags
    const int t = threadIdx.x, wid = t >> 6, lane = t & 63;
    const int lr = lane & 15, lg = lane >> 4;
    const int bid = blockIdx.y * 8 + blockIdx.x;           // grid (8, 64)
    const int swz = (bid & 7) * 64 + (bid >> 3);
    const int n0 = (swz & 7) << 7;
    const int m0 = (swz >> 3) << 6;
    const int wm = wid >> 1, wn = wid & 1;

    const int fa = wid;
    const int g0 = 2*wid, g1 = g0 + 1;
    const unsigned short* Ag  = A + (size_t)(m0 + fa*16 + lr)*DIM + lg*8;
    const unsigned short* Bg0 = W + (size_t)(n0 + g0*16 + lr)*DIM + lg*8;
    const unsigned short* Bg1 = W + (size_t)(n0 + g1*16 + lr)*DIM + lg*8;

    f32x4 acc[2][4] = {};

    gld16(Ag, &As[0][fa*512]);
    gld16(Bg0, &Bs[0][g0*512]); gld16(Bg1, &Bs[0][g1*512]);

    for (int it = 0; it < DIM/32; ++it) {
        __syncthreads();
        {
            const int nbf = (it+1)&1; const int ko = ((it+1)&31)*32;
            gld16(Ag + ko, &As[nbf][fa*512]);
            gld16(Bg0 + ko, &Bs[nbf][g0*512]); gld16(Bg1 + ko, &Bs[nbf][g1*512]);
        }
        const int cb = it & 1;
        short8 af[2], bf[4];
        #pragma unroll
        for (int i = 0; i < 2; ++i) af[i] = *(const short8*)&As[cb][(wm*2+i)*512 + lane*8];
        #pragma unroll
        for (int i = 0; i < 4; ++i) bf[i] = *(const short8*)&Bs[cb][(wn*4+i)*512 + lane*8];
        __builtin_amdgcn_s_setprio(1);
        #pragma unroll
        for (int mb = 0; mb < 2; ++mb)
            #pragma unroll
            for (int nb = 0; nb < 4; ++nb)
                acc[mb][nb] = __builtin_amdgcn_mfma_f32_16x16x32_bf16(af[mb], bf[nb], acc[mb][nb], 0, 0, 0);
        __builtin_amdgcn_s_setprio(0);
    }

    #pragma unroll
    for (int nb = 0; nb < 4; ++nb) {
        const int col = n0 + wn*64 + nb*16 + lr;
        const float bv = bias[col];
        #pragma unroll
        for (int mb = 0; mb < 2; ++mb) {
            #pragma unroll
            for (int j = 0; j < 4; ++j) {
                const int row = m0 + wm*32 + mb*16 + lg*4 + j;
                fo[(size_t)row*DIM + col] = acc[mb][nb][j] + bv;
            }
        }
    }
}

// ---------------- MFMA flash attention, 2-tile pipelined ----------------
// 256 thr (4 waves), block = 128 q rows of one (b,h); wave = 32 q rows.
// 4-buffer LDS rotation (64 KB), one barrier per TWO k-tiles.
struct PA { short8 p[4]; };

static __device__ __forceinline__ PA softmax_pack(const f32x16& s0, const f32x16& s1, float& lsum) {
    float rsum = 0.f;
    unsigned pw0[4][2], pw1[4][2];
    #pragma unroll
    for (int r1 = 0; r1 < 4; ++r1)
        #pragma unroll
        for (int tt = 0; tt < 2; ++tt) {
            float pa_ = __builtin_amdgcn_exp2f(s0[4*r1+2*tt]);
            float pb_ = __builtin_amdgcn_exp2f(s0[4*r1+2*tt+1]);
            float pc_ = __builtin_amdgcn_exp2f(s1[4*r1+2*tt]);
            float pd_ = __builtin_amdgcn_exp2f(s1[4*r1+2*tt+1]);
            rsum += (pa_ + pb_) + (pc_ + pd_);
            asm("v_cvt_pk_bf16_f32 %0, %1, %2" : "=v"(pw0[r1][tt]) : "v"(pa_), "v"(pb_));
            asm("v_cvt_pk_bf16_f32 %0, %1, %2" : "=v"(pw1[r1][tt]) : "v"(pc_), "v"(pd_));
        }
    rsum += __shfl_xor(rsum, 32);
    lsum += rsum;
    PA r;
    #pragma unroll
    for (int ss = 0; ss < 4; ++ss) {
        union { short8 s8; unsigned u[4]; } pu;
        #pragma unroll
        for (int tt = 0; tt < 2; ++tt) {
            const unsigned a = (ss >> 1) ? pw1[2*(ss&1)][tt]   : pw0[2*(ss&1)][tt];
            const unsigned b = (ss >> 1) ? pw1[2*(ss&1)+1][tt] : pw0[2*(ss&1)+1][tt];
            int2v sw = __builtin_amdgcn_permlane32_swap((int)a, (int)b, false, false);
            pu.u[tt]     = (unsigned)sw[0];
            pu.u[2 + tt] = (unsigned)sw[1];
        }
        r.p[ss] = pu.s8;
    }
    return r;
}

__global__ __launch_bounds__(256)
void attn_mfma2(const unsigned short* __restrict__ Q, const unsigned short* __restrict__ Kg,
                const unsigned short* __restrict__ Vt, unsigned short* __restrict__ O)
{
    __shared__ __align__(16) unsigned short Ks[4][4096];
    __shared__ __align__(16) unsigned short Vs[4][4096];
    const int t = threadIdx.x, wid = t >> 6, lane = t & 63;
    const int l31 = lane & 31, h = lane >> 5;
    // grid (16, 32) = 512 blocks; swizzle: XCD c gets heads 4c..4c+3
    const int bid = blockIdx.y * 16 + blockIdx.x;
    const int swz = (bid & 7) * 64 + (bid >> 3);
    const int qt = swz & 15, bh = swz >> 4;
    const int b = bh >> 4, hh = bh & 15;
    const size_t qkbase = (size_t)b*SEQ*DIM + (size_t)hh*HDIM;
    const unsigned short* Qb = Q + qkbase;
    const unsigned short* Kb = Kg + qkbase;
    const unsigned short* Vb = Vt + (size_t)bh*HDIM*VSTR;
    unsigned short*       Ob = O + qkbase;
    const int q0 = qt*128 + wid*32;

    short8 qf[4];   // Q as B-operand: lane holds Q[q0+l31][ds*16 + h*8 + e]
    #pragma unroll
    for (int ds = 0; ds < 4; ++ds)
        qf[ds] = *(const short8*)&Qb[(size_t)(q0 + l31)*DIM + ds*16 + h*8];

    const int f0 = 2*wid, f1 = f0 + 1;
    const unsigned short* Kg0 = &Kb[(size_t)((f0>>2)*32 + l31)*DIM + (f0&3)*16 + h*8];
    const unsigned short* Kg1 = &Kb[(size_t)((f1>>2)*32 + l31)*DIM + (f1&3)*16 + h*8];
    const unsigned short* Vg0 = &Vb[(size_t)((f0>>2)*32 + l31)*VSTR + (f0&3)*16 + h*8];
    const unsigned short* Vg1 = &Vb[(size_t)((f1>>2)*32 + l31)*VSTR + (f1&3)*16 + h*8];

    auto stage = [&](int tn) {
        const size_t koK = (size_t)tn * 64 * DIM;
        const size_t koV = (size_t)tn * 64;
        const int bb = tn & 3;
        gld16(Kg0 + koK, &Ks[bb][f0*512]); gld16(Kg1 + koK, &Ks[bb][f1*512]);
        gld16(Vg0 + koV, &Vs[bb][f0*512]); gld16(Vg1 + koV, &Vs[bb][f1*512]);
    };

    f32x16 ctx0 = {}, ctx1 = {};
    float lsum = 0.0f;

    stage(0); stage(1);

    for (int w = 0; w < SEQ/128; ++w) {
        const int t0 = 2*w;
        const int ba = t0 & 3, bb2 = (t0+1) & 3;
        __syncthreads();   // prev window's reads done; this window's bufs landed
        if (w + 1 < SEQ/128) { stage(t0+2); stage(t0+3); }

        // QK(t0)
        f32x16 s0a = {}, s1a = {};
        __builtin_amdgcn_s_setprio(1);
        #pragma unroll
        for (int ds = 0; ds < 4; ++ds) {
            short8 kf0 = *(const short8*)&Ks[ba][ds*512 + lane*8];
            short8 kf1 = *(const short8*)&Ks[ba][(4+ds)*512 + lane*8];
            s0a = mfma32(kf0, qf[ds], s0a);
            s1a = mfma32(kf1, qf[ds], s1a);
        }
        __builtin_amdgcn_s_setprio(0);

        PA pa = softmax_pack(s0a, s1a, lsum);

        // QK(t1) -- independent of sm(t0)/PV(t0); scheduler overlaps
        f32x16 s0b = {}, s1b = {};
        __builtin_amdgcn_s_setprio(1);
        #pragma unroll
        for (int ds = 0; ds < 4; ++ds) {
            short8 kf0 = *(const short8*)&Ks[bb2][ds*512 + lane*8];
            short8 kf1 = *(const short8*)&Ks[bb2][(4+ds)*512 + lane*8];
            s0b = mfma32(kf0, qf[ds], s0b);
            s1b = mfma32(kf1, qf[ds], s1b);
        }
        // PV(t0) -- MFMA pipe busy while sm(t1) VALU runs after
        #pragma unroll
        for (int ss = 0; ss < 4; ++ss) {
            short8 vf0 = *(const short8*)&Vs[ba][ss*512 + lane*8];
            short8 vf1 = *(const short8*)&Vs[ba][(4+ss)*512 + lane*8];
            ctx0 = mfma32(pa.p[ss], vf0, ctx0);
            ctx1 = mfma32(pa.p[ss], vf1, ctx1);
        }
        __builtin_amdgcn_s_setprio(0);

        PA pb = softmax_pack(s0b, s1b, lsum);

        // PV(t1)
        __builtin_amdgcn_s_setprio(1);
        #pragma unroll
        for (int ss = 0; ss < 4; ++ss) {
            short8 vf0 = *(const short8*)&Vs[bb2][ss*512 + lane*8];
            short8 vf1 = *(const short8*)&Vs[bb2][(4+ss)*512 + lane*8];
            ctx0 = mfma32(pb.p[ss], vf0, ctx0);
            ctx1 = mfma32(pb.p[ss], vf1, ctx1);
        }
        __builtin_amdgcn_s_setprio(0);
    }

    const float linv = 1.0f / lsum;
    #pragma unroll
    for (int r = 0; r < 16; ++r) {
        const int qrow = (r&3) + 8*(r>>2) + 4*h;
        const float nm = __shfl(linv, qrow);
        unsigned short* p = &Ob[(size_t)(q0 + qrow)*DIM + l31];
        p[0]  = bf16rne(ctx0[r] * nm);
        p[32] = bf16rne(ctx1[r] * nm);
    }
}

extern "C" void kernel_launch(void* const* d_in, const int* in_sizes, int n_in,
                              void* d_out, int out_size, void* d_ws, size_t ws_size,
                              hipStream_t stream) {
    const float* x  = (const float*)d_in[0];
    const float* wq = (const float*)d_in[1];
    const float* bq = (const float*)d_in[2];
    const float* wk = (const float*)d_in[3];
    const float* bk = (const float*)d_in[4];
    const float* wv = (const float*)d_in[5];
    const float* bv = (const float*)d_in[6];
    const float* wo = (const float*)d_in[7];
    const float* bo = (const float*)d_in[8];
    float* out = (float*)d_out;

    // ws (ushort): Xb/Cb 4M | Wq 1M | Wk 1M | Wv 1M | Wo 1M | Qb 4M | Kb 4M | Vtb 4.31M
    // Cb aliases Xb (x dead after QKV GEMM; attn writes Cb after reading Q/K/Vt).
    unsigned short* Xb  = (unsigned short*)d_ws;
    unsigned short* Wqb = Xb  + XN;
    unsigned short* Wkb = Wqb + WN;
    unsigned short* Wvb = Wkb + WN;
    unsigned short* Wob = Wvb + WN;
    unsigned short* Qb  = Wob + WN;
    unsigned short* Kb  = Qb  + XN;
    unsigned short* Vtb = Kb  + XN;
    unsigned short* Cb  = Xb;

    prep<<<4096, 256, 0, stream>>>(x, wq, wk, wv, wo, Xb);

    // V written directly transposed (VSTR-padded) -> no transpose kernel
    gemm_qkv<<<dim3(24, 32), 256, 0, stream>>>(Xb, Wqb, Wkb, Wvb, bq, bk, bv, Qb, Kb, Vtb);

    attn_mfma2<<<dim3(SEQ/128, BATCH*NHEADS), 256, 0, stream>>>(Qb, Kb, Vtb, Cb);

    gemm_o<<<dim3(8, 64), 256, 0, stream>>>(Cb, Wob, bo, out);
}

// Round 8
// 151.916 us; speedup vs baseline: 1.0555x; 1.0387x over previous
//
#include <hip/hip_runtime.h>

#define DIM 1024
#define NHEADS 16
#define HDIM 64
#define BATCH 2
#define SEQ 2048
#define MTOT (BATCH*SEQ)
// 1/sqrt(64) * log2(e), folded into Q so softmax uses exp2
#define QSCALE 0.18033688011112042f
#define XN ((size_t)MTOT*DIM)
#define WN ((size_t)DIM*DIM)

typedef __attribute__((ext_vector_type(8))) short short8;
typedef __attribute__((ext_vector_type(4))) float f32x4;
typedef __attribute__((ext_vector_type(16))) float f32x16;
typedef __attribute__((ext_vector_type(2))) int int2v;

static __device__ __forceinline__ unsigned short bf16rne(float f) {
    unsigned u = __builtin_bit_cast(unsigned, f);
    return (unsigned short)((u + 0x7fffu + ((u >> 16) & 1u)) >> 16);
}

// async global->LDS, 16B per lane; LDS dest must be wave-uniform (HW adds lane*16).
static __device__ __forceinline__ void gld16(const void* g, void* l) {
    __builtin_amdgcn_global_load_lds((const __attribute__((address_space(1))) void*)g,
                                     (__attribute__((address_space(3))) void*)l, 16, 0, 0);
}

static __device__ __forceinline__ f32x16 mfma32(short8 a, short8 b, f32x16 c) {
    return __builtin_amdgcn_mfma_f32_32x32x16_bf16(a, b, c, 0, 0, 0);
}

// ---------------- fused f32 -> bf16 convert of x + 4 weights ----------------
__global__ __launch_bounds__(256)
void prep(const float* __restrict__ x, const float* __restrict__ wq, const float* __restrict__ wk,
          const float* __restrict__ wv, const float* __restrict__ wo, unsigned short* __restrict__ dst)
{
    const size_t i = ((size_t)blockIdx.x*256 + threadIdx.x)*8;
    const float* s; size_t o;
    if (i < XN)           { s = x;  o = i; }
    else if (i < XN+WN)   { s = wq; o = i - XN; }
    else if (i < XN+2*WN) { s = wk; o = i - XN - WN; }
    else if (i < XN+3*WN) { s = wv; o = i - XN - 2*WN; }
    else                  { s = wo; o = i - XN - 3*WN; }
    float4 a = *(const float4*)(s + o);
    float4 b = *(const float4*)(s + o + 4);
    uint4 w;
    w.x = (unsigned)bf16rne(a.x) | ((unsigned)bf16rne(a.y) << 16);
    w.y = (unsigned)bf16rne(a.z) | ((unsigned)bf16rne(a.w) << 16);
    w.z = (unsigned)bf16rne(b.x) | ((unsigned)bf16rne(b.y) << 16);
    w.w = (unsigned)bf16rne(b.z) | ((unsigned)bf16rne(b.w) << 16);
    *(uint4*)&dst[i] = w;
}

// ---------------- fused QKV bf16 GEMM, pipelined K-loop (counted vmcnt) ----------------
// 128x128 tile, BK=32, 256 thr (4 waves 2x2), wave tile 64x64.
// 4-deep LDS ring, depth-3 prefetch, ONE raw s_barrier per iter, s_waitcnt vmcnt(8):
// loads stay in flight across barriers (T3/T4) instead of __syncthreads' vmcnt(0) drain.
__global__ __launch_bounds__(256)
void gemm_qkv(const unsigned short* __restrict__ A,
              const unsigned short* __restrict__ W0, const unsigned short* __restrict__ W1,
              const unsigned short* __restrict__ W2,
              const float* __restrict__ b0, const float* __restrict__ b1, const float* __restrict__ b2,
              unsigned short* __restrict__ o0, unsigned short* __restrict__ o1, unsigned short* __restrict__ o2)
{
    __shared__ __align__(16) unsigned short As[4][4096];
    __shared__ __align__(16) unsigned short Bs[4][4096];
    const int t = threadIdx.x, wid = t >> 6, lane = t & 63;
    const int lr = lane & 15, lg = lane >> 4;
    // XCD swizzle: 768 blocks, XCD c gets 4 consecutive m-panels (1 MB A) + all W (6 MB)
    const int bid = blockIdx.y * 24 + blockIdx.x;
    const int swz = (bid & 7) * 96 + (bid >> 3);
    const int sx = swz % 24, sy = swz / 24;
    const int widx = sx >> 3;
    const int n0 = (sx & 7) << 7;
    const int m0 = sy << 7;
    const unsigned short* W = widx == 0 ? W0 : (widx == 1 ? W1 : W2);
    const float* bias        = widx == 0 ? b0 : (widx == 1 ? b1 : b2);
    const float scale        = widx == 0 ? QSCALE : 1.0f;
    unsigned short* out      = widx == 0 ? o0 : (widx == 1 ? o1 : o2);

    const int wm = wid >> 1, wn = wid & 1;
    const int f0 = 2*wid, f1 = f0 + 1;
    const unsigned short* Ag0 = A + (size_t)(m0 + f0*16 + lr)*DIM + lg*8;
    const unsigned short* Ag1 = A + (size_t)(m0 + f1*16 + lr)*DIM + lg*8;
    const unsigned short* Bg0 = W + (size_t)(n0 + f0*16 + lr)*DIM + lg*8;
    const unsigned short* Bg1 = W + (size_t)(n0 + f1*16 + lr)*DIM + lg*8;

    auto stage = [&](int tt) {   // 4 gld16 into ring slot tt&3 (K-offset wraps at tail)
        const int ko = (tt & 31) * 32;
        const int bb = tt & 3;
        gld16(Ag0 + ko, &As[bb][f0*512]); gld16(Ag1 + ko, &As[bb][f1*512]);
        gld16(Bg0 + ko, &Bs[bb][f0*512]); gld16(Bg1 + ko, &Bs[bb][f1*512]);
    };

    f32x4 acc[4][4] = {};
    stage(0); stage(1); stage(2);   // 12 loads in flight

    for (int it = 0; it < DIM/32; ++it) {
        // oldest 4 loads (ring slot it&3) complete; others remain in flight
        asm volatile("s_waitcnt vmcnt(8)" ::: "memory");
        __builtin_amdgcn_s_barrier();   // all waves' slot-it fragments landed; slot it-1 free
        const int cb = it & 3;
        short8 af[4], bf[4];
        #pragma unroll
        for (int i = 0; i < 4; ++i) af[i] = *(const short8*)&As[cb][(wm*4+i)*512 + lane*8];
        #pragma unroll
        for (int i = 0; i < 4; ++i) bf[i] = *(const short8*)&Bs[cb][(wn*4+i)*512 + lane*8];
        stage(it + 3);   // refill; write-hazard gated by this iter's barrier
        __builtin_amdgcn_s_setprio(1);
        #pragma unroll
        for (int mb = 0; mb < 4; ++mb)
            #pragma unroll
            for (int nb = 0; nb < 4; ++nb)
                acc[mb][nb] = __builtin_amdgcn_mfma_f32_16x16x32_bf16(af[mb], bf[nb], acc[mb][nb], 0, 0, 0);
        __builtin_amdgcn_s_setprio(0);
    }

    #pragma unroll
    for (int nb = 0; nb < 4; ++nb) {
        const int col = n0 + wn*64 + nb*16 + lr;
        const float bv = bias[col];
        #pragma unroll
        for (int mb = 0; mb < 4; ++mb) {
            #pragma unroll
            for (int j = 0; j < 4; ++j) {
                const int row = m0 + wm*64 + mb*16 + lg*4 + j;
                out[(size_t)row*DIM + col] = bf16rne((acc[mb][nb][j] + bv) * scale);
            }
        }
    }
}

// ---------------- O-projection GEMM: 64x128 tile, pipelined K-loop, f32 out ----------------
__global__ __launch_bounds__(256)
void gemm_o(const unsigned short* __restrict__ A, const unsigned short* __restrict__ W,
            const float* __restrict__ bias, float* __restrict__ fo)
{
    __shared__ __align__(16) unsigned short As[4][2048];   // 4 frags / slot
    __shared__ __align__(16) unsigned short Bs[4][4096];   // 8 frags / slot
    const int t = threadIdx.x, wid = t >> 6, lane = t & 63;
    const int lr = lane & 15, lg = lane >> 4;
    const int bid = blockIdx.y * 8 + blockIdx.x;           // grid (8, 64) = 512 blocks
    const int swz = (bid & 7) * 64 + (bid >> 3);
    const int n0 = (swz & 7) << 7;
    const int m0 = (swz >> 3) << 6;
    const int wm = wid >> 1, wn = wid & 1;

    const int fa = wid;
    const int g0 = 2*wid, g1 = g0 + 1;
    const unsigned short* Ag  = A + (size_t)(m0 + fa*16 + lr)*DIM + lg*8;
    const unsigned short* Bg0 = W + (size_t)(n0 + g0*16 + lr)*DIM + lg*8;
    const unsigned short* Bg1 = W + (size_t)(n0 + g1*16 + lr)*DIM + lg*8;

    auto stage = [&](int tt) {   // 3 gld16 per slot
        const int ko = (tt & 31) * 32;
        const int bb = tt & 3;
        gld16(Ag + ko, &As[bb][fa*512]);
        gld16(Bg0 + ko, &Bs[bb][g0*512]); gld16(Bg1 + ko, &Bs[bb][g1*512]);
    };

    f32x4 acc[2][4] = {};
    stage(0); stage(1); stage(2);   // 9 loads in flight

    for (int it = 0; it < DIM/32; ++it) {
        asm volatile("s_waitcnt vmcnt(6)" ::: "memory");
        __builtin_amdgcn_s_barrier();
        const int cb = it & 3;
        short8 af[2], bf[4];
        #pragma unroll
        for (int i = 0; i < 2; ++i) af[i] = *(const short8*)&As[cb][(wm*2+i)*512 + lane*8];
        #pragma unroll
        for (int i = 0; i < 4; ++i) bf[i] = *(const short8*)&Bs[cb][(wn*4+i)*512 + lane*8];
        stage(it + 3);
        __builtin_amdgcn_s_setprio(1);
        #pragma unroll
        for (int mb = 0; mb < 2; ++mb)
            #pragma unroll
            for (int nb = 0; nb < 4; ++nb)
                acc[mb][nb] = __builtin_amdgcn_mfma_f32_16x16x32_bf16(af[mb], bf[nb], acc[mb][nb], 0, 0, 0);
        __builtin_amdgcn_s_setprio(0);
    }

    #pragma unroll
    for (int nb = 0; nb < 4; ++nb) {
        const int col = n0 + wn*64 + nb*16 + lr;
        const float bv = bias[col];
        #pragma unroll
        for (int mb = 0; mb < 2; ++mb) {
            #pragma unroll
            for (int j = 0; j < 4; ++j) {
                const int row = m0 + wm*32 + mb*16 + lg*4 + j;
                fo[(size_t)row*DIM + col] = acc[mb][nb][j] + bv;
            }
        }
    }
}

// ---------------- V transpose: [b,s,h,d] -> [b,h,d,s] ----------------
__global__ __launch_bounds__(256)
void transpose_v(const unsigned short* __restrict__ V, unsigned short* __restrict__ Vt)
{
    __shared__ unsigned short tile[64][66];
    const int t  = threadIdx.x;
    const int st = blockIdx.x;
    const int bh = blockIdx.y;
    const int b = bh >> 4, h = bh & 15;
    const int sr = t >> 3;
    const int dc = (t & 7) * 8;

    #pragma unroll
    for (int r = 0; r < 2; ++r) {
        const int s = r*32 + sr;
        short8 v = *(const short8*)(V + (size_t)(b*SEQ + st*64 + s)*DIM + h*HDIM + dc);
        #pragma unroll
        for (int e = 0; e < 8; ++e) tile[s][dc + e] = (unsigned short)v[e];
    }
    __syncthreads();
    #pragma unroll
    for (int r = 0; r < 2; ++r) {
        const int d = r*32 + sr;
        short8 ov;
        #pragma unroll
        for (int e = 0; e < 8; ++e) ov[e] = (short)tile[dc + e][d];
        *(short8*)(Vt + (size_t)bh*HDIM*SEQ + (size_t)d*SEQ + st*64 + dc) = ov;
    }
}

// ---------------- MFMA flash attention, 2-tile pipelined ----------------
// 256 thr (4 waves), block = 128 q rows of one (b,h); wave = 32 q rows.
// 4-buffer LDS rotation (64 KB), one barrier per TWO k-tiles.
struct PA { short8 p[4]; };

static __device__ __forceinline__ PA softmax_pack(const f32x16& s0, const f32x16& s1, float& lsum) {
    float rsum = 0.f;
    unsigned pw0[4][2], pw1[4][2];
    #pragma unroll
    for (int r1 = 0; r1 < 4; ++r1)
        #pragma unroll
        for (int tt = 0; tt < 2; ++tt) {
            float pa_ = __builtin_amdgcn_exp2f(s0[4*r1+2*tt]);
            float pb_ = __builtin_amdgcn_exp2f(s0[4*r1+2*tt+1]);
            float pc_ = __builtin_amdgcn_exp2f(s1[4*r1+2*tt]);
            float pd_ = __builtin_amdgcn_exp2f(s1[4*r1+2*tt+1]);
            rsum += (pa_ + pb_) + (pc_ + pd_);
            asm("v_cvt_pk_bf16_f32 %0, %1, %2" : "=v"(pw0[r1][tt]) : "v"(pa_), "v"(pb_));
            asm("v_cvt_pk_bf16_f32 %0, %1, %2" : "=v"(pw1[r1][tt]) : "v"(pc_), "v"(pd_));
        }
    rsum += __shfl_xor(rsum, 32);
    lsum += rsum;
    PA r;
    #pragma unroll
    for (int ss = 0; ss < 4; ++ss) {
        union { short8 s8; unsigned u[4]; } pu;
        #pragma unroll
        for (int tt = 0; tt < 2; ++tt) {
            const unsigned a = (ss >> 1) ? pw1[2*(ss&1)][tt]   : pw0[2*(ss&1)][tt];
            const unsigned b = (ss >> 1) ? pw1[2*(ss&1)+1][tt] : pw0[2*(ss&1)+1][tt];
            int2v sw = __builtin_amdgcn_permlane32_swap((int)a, (int)b, false, false);
            pu.u[tt]     = (unsigned)sw[0];
            pu.u[2 + tt] = (unsigned)sw[1];
        }
        r.p[ss] = pu.s8;
    }
    return r;
}

__global__ __launch_bounds__(256)
void attn_mfma2(const unsigned short* __restrict__ Q, const unsigned short* __restrict__ Kg,
                const unsigned short* __restrict__ Vt, unsigned short* __restrict__ O)
{
    __shared__ __align__(16) unsigned short Ks[4][4096];
    __shared__ __align__(16) unsigned short Vs[4][4096];
    const int t = threadIdx.x, wid = t >> 6, lane = t & 63;
    const int l31 = lane & 31, h = lane >> 5;
    // grid (16, 32) = 512 blocks; swizzle: XCD c gets heads 4c..4c+3
    const int bid = blockIdx.y * 16 + blockIdx.x;
    const int swz = (bid & 7) * 64 + (bid >> 3);
    const int qt = swz & 15, bh = swz >> 4;
    const int b = bh >> 4, hh = bh & 15;
    const size_t qkbase = (size_t)b*SEQ*DIM + (size_t)hh*HDIM;
    const unsigned short* Qb = Q + qkbase;
    const unsigned short* Kb = Kg + qkbase;
    const unsigned short* Vb = Vt + (size_t)bh*HDIM*SEQ;
    unsigned short*       Ob = O + qkbase;
    const int q0 = qt*128 + wid*32;

    short8 qf[4];   // Q as B-operand: lane holds Q[q0+l31][ds*16 + h*8 + e]
    #pragma unroll
    for (int ds = 0; ds < 4; ++ds)
        qf[ds] = *(const short8*)&Qb[(size_t)(q0 + l31)*DIM + ds*16 + h*8];

    const int f0 = 2*wid, f1 = f0 + 1;
    const unsigned short* Kg0 = &Kb[(size_t)((f0>>2)*32 + l31)*DIM + (f0&3)*16 + h*8];
    const unsigned short* Kg1 = &Kb[(size_t)((f1>>2)*32 + l31)*DIM + (f1&3)*16 + h*8];
    const unsigned short* Vg0 = &Vb[(size_t)((f0>>2)*32 + l31)*SEQ + (f0&3)*16 + h*8];
    const unsigned short* Vg1 = &Vb[(size_t)((f1>>2)*32 + l31)*SEQ + (f1&3)*16 + h*8];

    auto stage = [&](int tn) {
        const size_t koK = (size_t)tn * 64 * DIM;
        const size_t koV = (size_t)tn * 64;
        const int bb = tn & 3;
        gld16(Kg0 + koK, &Ks[bb][f0*512]); gld16(Kg1 + koK, &Ks[bb][f1*512]);
        gld16(Vg0 + koV, &Vs[bb][f0*512]); gld16(Vg1 + koV, &Vs[bb][f1*512]);
    };

    f32x16 ctx0 = {}, ctx1 = {};
    float lsum = 0.0f;

    stage(0); stage(1);

    for (int w = 0; w < SEQ/128; ++w) {
        const int t0 = 2*w;
        const int ba = t0 & 3, bb2 = (t0+1) & 3;
        __syncthreads();   // prev window's reads done; this window's bufs landed
        if (w + 1 < SEQ/128) { stage(t0+2); stage(t0+3); }

        // QK(t0)
        f32x16 s0a = {}, s1a = {};
        __builtin_amdgcn_s_setprio(1);
        #pragma unroll
        for (int ds = 0; ds < 4; ++ds) {
            short8 kf0 = *(const short8*)&Ks[ba][ds*512 + lane*8];
            short8 kf1 = *(const short8*)&Ks[ba][(4+ds)*512 + lane*8];
            s0a = mfma32(kf0, qf[ds], s0a);
            s1a = mfma32(kf1, qf[ds], s1a);
        }
        __builtin_amdgcn_s_setprio(0);

        PA pa = softmax_pack(s0a, s1a, lsum);

        // QK(t1) -- independent of sm(t0)/PV(t0); scheduler overlaps
        f32x16 s0b = {}, s1b = {};
        __builtin_amdgcn_s_setprio(1);
        #pragma unroll
        for (int ds = 0; ds < 4; ++ds) {
            short8 kf0 = *(const short8*)&Ks[bb2][ds*512 + lane*8];
            short8 kf1 = *(const short8*)&Ks[bb2][(4+ds)*512 + lane*8];
            s0b = mfma32(kf0, qf[ds], s0b);
            s1b = mfma32(kf1, qf[ds], s1b);
        }
        // PV(t0) -- MFMA pipe busy while sm(t1) VALU runs after
        #pragma unroll
        for (int ss = 0; ss < 4; ++ss) {
            short8 vf0 = *(const short8*)&Vs[ba][ss*512 + lane*8];
            short8 vf1 = *(const short8*)&Vs[ba][(4+ss)*512 + lane*8];
            ctx0 = mfma32(pa.p[ss], vf0, ctx0);
            ctx1 = mfma32(pa.p[ss], vf1, ctx1);
        }
        __builtin_amdgcn_s_setprio(0);

        PA pb = softmax_pack(s0b, s1b, lsum);

        // PV(t1)
        __builtin_amdgcn_s_setprio(1);
        #pragma unroll
        for (int ss = 0; ss < 4; ++ss) {
            short8 vf0 = *(const short8*)&Vs[bb2][ss*512 + lane*8];
            short8 vf1 = *(const short8*)&Vs[bb2][(4+ss)*512 + lane*8];
            ctx0 = mfma32(pb.p[ss], vf0, ctx0);
            ctx1 = mfma32(pb.p[ss], vf1, ctx1);
        }
        __builtin_amdgcn_s_setprio(0);
    }

    const float linv = 1.0f / lsum;
    #pragma unroll
    for (int r = 0; r < 16; ++r) {
        const int qrow = (r&3) + 8*(r>>2) + 4*h;
        const float nm = __shfl(linv, qrow);
        unsigned short* p = &Ob[(size_t)(q0 + qrow)*DIM + l31];
        p[0]  = bf16rne(ctx0[r] * nm);
        p[32] = bf16rne(ctx1[r] * nm);
    }
}

extern "C" void kernel_launch(void* const* d_in, const int* in_sizes, int n_in,
                              void* d_out, int out_size, void* d_ws, size_t ws_size,
                              hipStream_t stream) {
    const float* x  = (const float*)d_in[0];
    const float* wq = (const float*)d_in[1];
    const float* bq = (const float*)d_in[2];
    const float* wk = (const float*)d_in[3];
    const float* bk = (const float*)d_in[4];
    const float* wv = (const float*)d_in[5];
    const float* bv = (const float*)d_in[6];
    const float* wo = (const float*)d_in[7];
    const float* bo = (const float*)d_in[8];
    float* out = (float*)d_out;

    // ws (ushort): Xb/Cb 4M | Wq 1M | Wk 1M | Wv 1M | Wo 1M | Qb 4M | Kb 4M | Vb 4M | Vtb 4M = 48 MB
    // Cb aliases Xb (x dead after QKV GEMM; attn writes Cb after reading Q/K/Vt).
    unsigned short* Xb  = (unsigned short*)d_ws;
    unsigned short* Wqb = Xb  + XN;
    unsigned short* Wkb = Wqb + WN;
    unsigned short* Wvb = Wkb + WN;
    unsigned short* Wob = Wvb + WN;
    unsigned short* Qb  = Wob + WN;
    unsigned short* Kb  = Qb  + XN;
    unsigned short* Vb  = Kb  + XN;
    unsigned short* Vtb = Vb  + XN;
    unsigned short* Cb  = Xb;

    prep<<<4096, 256, 0, stream>>>(x, wq, wk, wv, wo, Xb);

    gemm_qkv<<<dim3(24, 32), 256, 0, stream>>>(Xb, Wqb, Wkb, Wvb, bq, bk, bv, Qb, Kb, Vb);

    transpose_v<<<dim3(SEQ/64, BATCH*NHEADS), 256, 0, stream>>>(Vb, Vtb);
    attn_mfma2<<<dim3(SEQ/128, BATCH*NHEADS), 256, 0, stream>>>(Qb, Kb, Vtb, Cb);

    gemm_o<<<dim3(8, 64), 256, 0, stream>>>(Cb, Wob, bo, out);
}

// Round 9
// 141.898 us; speedup vs baseline: 1.1300x; 1.0706x over previous
//
#include <hip/hip_runtime.h>

#define DIM 1024
#define NHEADS 16
#define HDIM 64
#define BATCH 2
#define SEQ 2048
#define MTOT (BATCH*SEQ)
// 1/sqrt(64) * log2(e), folded into Q so softmax uses exp2
#define QSCALE 0.18033688011112042f
#define XN ((size_t)MTOT*DIM)
#define WN ((size_t)DIM*DIM)

typedef __attribute__((ext_vector_type(8))) short short8;
typedef __attribute__((ext_vector_type(4))) float f32x4;
typedef __attribute__((ext_vector_type(16))) float f32x16;
typedef __attribute__((ext_vector_type(2))) int int2v;

static __device__ __forceinline__ unsigned short bf16rne(float f) {
    unsigned u = __builtin_bit_cast(unsigned, f);
    return (unsigned short)((u + 0x7fffu + ((u >> 16) & 1u)) >> 16);
}

// async global->LDS, 16B per lane; LDS dest must be wave-uniform (HW adds lane*16).
static __device__ __forceinline__ void gld16(const void* g, void* l) {
    __builtin_amdgcn_global_load_lds((const __attribute__((address_space(1))) void*)g,
                                     (__attribute__((address_space(3))) void*)l, 16, 0, 0);
}

static __device__ __forceinline__ f32x16 mfma32(short8 a, short8 b, f32x16 c) {
    return __builtin_amdgcn_mfma_f32_32x32x16_bf16(a, b, c, 0, 0, 0);
}

// ---------------- fused f32 -> bf16 convert of x + 4 weights ----------------
__global__ __launch_bounds__(256)
void prep(const float* __restrict__ x, const float* __restrict__ wq, const float* __restrict__ wk,
          const float* __restrict__ wv, const float* __restrict__ wo, unsigned short* __restrict__ dst)
{
    const size_t i = ((size_t)blockIdx.x*256 + threadIdx.x)*8;
    const float* s; size_t o;
    if (i < XN)           { s = x;  o = i; }
    else if (i < XN+WN)   { s = wq; o = i - XN; }
    else if (i < XN+2*WN) { s = wk; o = i - XN - WN; }
    else if (i < XN+3*WN) { s = wv; o = i - XN - 2*WN; }
    else                  { s = wo; o = i - XN - 3*WN; }
    float4 a = *(const float4*)(s + o);
    float4 b = *(const float4*)(s + o + 4);
    uint4 w;
    w.x = (unsigned)bf16rne(a.x) | ((unsigned)bf16rne(a.y) << 16);
    w.y = (unsigned)bf16rne(a.z) | ((unsigned)bf16rne(a.w) << 16);
    w.z = (unsigned)bf16rne(b.x) | ((unsigned)bf16rne(b.y) << 16);
    w.w = (unsigned)bf16rne(b.z) | ((unsigned)bf16rne(b.w) << 16);
    *(uint4*)&dst[i] = w;
}

// ---------------- fused QKV bf16 GEMM, counted-vmcnt pipeline, 3 blocks/CU ----------------
// 128x128 tile, BK=32, 256 thr (4 waves 2x2), wave tile 64x64.
// 3-slot LDS ring (48 KB -> 3 blocks/CU; 768 blocks = exactly 3/CU), depth-2 prefetch,
// per-iter: vmcnt(4) [own slot-it loads landed] -> s_barrier [all waves'] -> reads ->
// guarded stage(it+2) -> MFMA. Tail iters drain vmcnt(0); no stage past K (endpgm hazard).
__global__ __launch_bounds__(256)
void gemm_qkv(const unsigned short* __restrict__ A,
              const unsigned short* __restrict__ W0, const unsigned short* __restrict__ W1,
              const unsigned short* __restrict__ W2,
              const float* __restrict__ b0, const float* __restrict__ b1, const float* __restrict__ b2,
              unsigned short* __restrict__ o0, unsigned short* __restrict__ o1, unsigned short* __restrict__ o2)
{
    __shared__ __align__(16) unsigned short As[3][4096];
    __shared__ __align__(16) unsigned short Bs[3][4096];
    const int t = threadIdx.x, wid = t >> 6, lane = t & 63;
    const int lr = lane & 15, lg = lane >> 4;
    // XCD swizzle: 768 blocks, XCD c gets 4 consecutive m-panels (1 MB A) + all W
    const int bid = blockIdx.y * 24 + blockIdx.x;
    const int swz = (bid & 7) * 96 + (bid >> 3);
    const int sx = swz % 24, sy = swz / 24;
    const int widx = sx >> 3;
    const int n0 = (sx & 7) << 7;
    const int m0 = sy << 7;
    const unsigned short* W = widx == 0 ? W0 : (widx == 1 ? W1 : W2);
    const float* bias        = widx == 0 ? b0 : (widx == 1 ? b1 : b2);
    const float scale        = widx == 0 ? QSCALE : 1.0f;
    unsigned short* out      = widx == 0 ? o0 : (widx == 1 ? o1 : o2);

    const int wm = wid >> 1, wn = wid & 1;
    const int f0 = 2*wid, f1 = f0 + 1;
    const unsigned short* Ag0 = A + (size_t)(m0 + f0*16 + lr)*DIM + lg*8;
    const unsigned short* Ag1 = A + (size_t)(m0 + f1*16 + lr)*DIM + lg*8;
    const unsigned short* Bg0 = W + (size_t)(n0 + f0*16 + lr)*DIM + lg*8;
    const unsigned short* Bg1 = W + (size_t)(n0 + f1*16 + lr)*DIM + lg*8;

    auto stage = [&](int tt, int slot) {   // 4 gld16; tt < 32 guaranteed by caller
        const int ko = tt * 32;
        gld16(Ag0 + ko, &As[slot][f0*512]); gld16(Ag1 + ko, &As[slot][f1*512]);
        gld16(Bg0 + ko, &Bs[slot][f0*512]); gld16(Bg1 + ko, &Bs[slot][f1*512]);
    };

    f32x4 acc[4][4] = {};
    stage(0, 0); stage(1, 1);   // 8 loads in flight
    int c0 = 0, c1 = 1, c2 = 2; // ring: current, next, stage-target

    for (int it = 0; it < DIM/32; ++it) {
        if (it < DIM/32 - 2) { asm volatile("s_waitcnt vmcnt(4)" ::: "memory"); }
        else                 { asm volatile("s_waitcnt vmcnt(0)" ::: "memory"); }
        __builtin_amdgcn_s_barrier();   // all waves' slot-it data landed; slot it-1 free
        short8 af[4], bf[4];
        #pragma unroll
        for (int i = 0; i < 4; ++i) af[i] = *(const short8*)&As[c0][(wm*4+i)*512 + lane*8];
        #pragma unroll
        for (int i = 0; i < 4; ++i) bf[i] = *(const short8*)&Bs[c0][(wn*4+i)*512 + lane*8];
        if (it + 2 < DIM/32) stage(it + 2, c2);
        __builtin_amdgcn_s_setprio(1);
        #pragma unroll
        for (int mb = 0; mb < 4; ++mb)
            #pragma unroll
            for (int nb = 0; nb < 4; ++nb)
                acc[mb][nb] = __builtin_amdgcn_mfma_f32_16x16x32_bf16(af[mb], bf[nb], acc[mb][nb], 0, 0, 0);
        __builtin_amdgcn_s_setprio(0);
        const int tmp = c0; c0 = c1; c1 = c2; c2 = tmp;
    }

    #pragma unroll
    for (int nb = 0; nb < 4; ++nb) {
        const int col = n0 + wn*64 + nb*16 + lr;
        const float bv = bias[col];
        #pragma unroll
        for (int mb = 0; mb < 4; ++mb) {
            #pragma unroll
            for (int j = 0; j < 4; ++j) {
                const int row = m0 + wm*64 + mb*16 + lg*4 + j;
                out[(size_t)row*DIM + col] = bf16rne((acc[mb][nb][j] + bv) * scale);
            }
        }
    }
}

// ---------------- O-projection GEMM: 64x128 tile, counted-vmcnt, f32 out ----------------
__global__ __launch_bounds__(256)
void gemm_o(const unsigned short* __restrict__ A, const unsigned short* __restrict__ W,
            const float* __restrict__ bias, float* __restrict__ fo)
{
    __shared__ __align__(16) unsigned short As[3][2048];
    __shared__ __align__(16) unsigned short Bs[3][4096];
    const int t = threadIdx.x, wid = t >> 6, lane = t & 63;
    const int lr = lane & 15, lg = lane >> 4;
    const int bid = blockIdx.y * 8 + blockIdx.x;           // grid (8, 64) = 512 blocks
    const int swz = (bid & 7) * 64 + (bid >> 3);
    const int n0 = (swz & 7) << 7;
    const int m0 = (swz >> 3) << 6;
    const int wm = wid >> 1, wn = wid & 1;

    const int fa = wid;
    const int g0 = 2*wid, g1 = g0 + 1;
    const unsigned short* Ag  = A + (size_t)(m0 + fa*16 + lr)*DIM + lg*8;
    const unsigned short* Bg0 = W + (size_t)(n0 + g0*16 + lr)*DIM + lg*8;
    const unsigned short* Bg1 = W + (size_t)(n0 + g1*16 + lr)*DIM + lg*8;

    auto stage = [&](int tt, int slot) {   // 3 gld16
        const int ko = tt * 32;
        gld16(Ag + ko, &As[slot][fa*512]);
        gld16(Bg0 + ko, &Bs[slot][g0*512]); gld16(Bg1 + ko, &Bs[slot][g1*512]);
    };

    f32x4 acc[2][4] = {};
    stage(0, 0); stage(1, 1);   // 6 loads in flight
    int c0 = 0, c1 = 1, c2 = 2;

    for (int it = 0; it < DIM/32; ++it) {
        if (it < DIM/32 - 2) { asm volatile("s_waitcnt vmcnt(3)" ::: "memory"); }
        else                 { asm volatile("s_waitcnt vmcnt(0)" ::: "memory"); }
        __builtin_amdgcn_s_barrier();
        short8 af[2], bf[4];
        #pragma unroll
        for (int i = 0; i < 2; ++i) af[i] = *(const short8*)&As[c0][(wm*2+i)*512 + lane*8];
        #pragma unroll
        for (int i = 0; i < 4; ++i) bf[i] = *(const short8*)&Bs[c0][(wn*4+i)*512 + lane*8];
        if (it + 2 < DIM/32) stage(it + 2, c2);
        __builtin_amdgcn_s_setprio(1);
        #pragma unroll
        for (int mb = 0; mb < 2; ++mb)
            #pragma unroll
            for (int nb = 0; nb < 4; ++nb)
                acc[mb][nb] = __builtin_amdgcn_mfma_f32_16x16x32_bf16(af[mb], bf[nb], acc[mb][nb], 0, 0, 0);
        __builtin_amdgcn_s_setprio(0);
        const int tmp = c0; c0 = c1; c1 = c2; c2 = tmp;
    }

    #pragma unroll
    for (int nb = 0; nb < 4; ++nb) {
        const int col = n0 + wn*64 + nb*16 + lr;
        const float bv = bias[col];
        #pragma unroll
        for (int mb = 0; mb < 2; ++mb) {
            #pragma unroll
            for (int j = 0; j < 4; ++j) {
                const int row = m0 + wm*32 + mb*16 + lg*4 + j;
                fo[(size_t)row*DIM + col] = acc[mb][nb][j] + bv;
            }
        }
    }
}

// ---------------- V transpose: [b,s,h,d] -> [b,h,d,s] ----------------
__global__ __launch_bounds__(256)
void transpose_v(const unsigned short* __restrict__ V, unsigned short* __restrict__ Vt)
{
    __shared__ unsigned short tile[64][66];
    const int t  = threadIdx.x;
    const int st = blockIdx.x;
    const int bh = blockIdx.y;
    const int b = bh >> 4, h = bh & 15;
    const int sr = t >> 3;
    const int dc = (t & 7) * 8;

    #pragma unroll
    for (int r = 0; r < 2; ++r) {
        const int s = r*32 + sr;
        short8 v = *(const short8*)(V + (size_t)(b*SEQ + st*64 + s)*DIM + h*HDIM + dc);
        #pragma unroll
        for (int e = 0; e < 8; ++e) tile[s][dc + e] = (unsigned short)v[e];
    }
    __syncthreads();
    #pragma unroll
    for (int r = 0; r < 2; ++r) {
        const int d = r*32 + sr;
        short8 ov;
        #pragma unroll
        for (int e = 0; e < 8; ++e) ov[e] = (short)tile[dc + e][d];
        *(short8*)(Vt + (size_t)bh*HDIM*SEQ + (size_t)d*SEQ + st*64 + dc) = ov;
    }
}

// ---------------- MFMA flash attention, 2-tile pipelined, counted vmcnt ----------------
// 256 thr (4 waves), block = 128 q rows of one (b,h); wave = 32 q rows.
// 4-buffer LDS ring. Per window (2 tiles): B1[vmcnt(4)+bar] -> stage(t0+2) -> QK(t0) ->
// sm(t0) -> B2[vmcnt(4)+bar] -> stage(t0+3) -> QK(t1) -> PV(t0) -> sm(t1) -> PV(t1).
// Hazards: stage(t0+2) writes slot t0-2 (reads done <= B1 of this window);
// stage(t0+3) writes slot t0-1 (reads done <= B1); vmcnt(4) before each barrier drains
// own oldest stage (t0 resp. t0+1) -> barrier makes it block-wide. Loads fly ~1.5 windows.
struct PA { short8 p[4]; };

static __device__ __forceinline__ PA softmax_pack(const f32x16& s0, const f32x16& s1, float& lsum) {
    float rsum = 0.f;
    unsigned pw0[4][2], pw1[4][2];
    #pragma unroll
    for (int r1 = 0; r1 < 4; ++r1)
        #pragma unroll
        for (int tt = 0; tt < 2; ++tt) {
            float pa_ = __builtin_amdgcn_exp2f(s0[4*r1+2*tt]);
            float pb_ = __builtin_amdgcn_exp2f(s0[4*r1+2*tt+1]);
            float pc_ = __builtin_amdgcn_exp2f(s1[4*r1+2*tt]);
            float pd_ = __builtin_amdgcn_exp2f(s1[4*r1+2*tt+1]);
            rsum += (pa_ + pb_) + (pc_ + pd_);
            asm("v_cvt_pk_bf16_f32 %0, %1, %2" : "=v"(pw0[r1][tt]) : "v"(pa_), "v"(pb_));
            asm("v_cvt_pk_bf16_f32 %0, %1, %2" : "=v"(pw1[r1][tt]) : "v"(pc_), "v"(pd_));
        }
    rsum += __shfl_xor(rsum, 32);
    lsum += rsum;
    PA r;
    #pragma unroll
    for (int ss = 0; ss < 4; ++ss) {
        union { short8 s8; unsigned u[4]; } pu;
        #pragma unroll
        for (int tt = 0; tt < 2; ++tt) {
            const unsigned a = (ss >> 1) ? pw1[2*(ss&1)][tt]   : pw0[2*(ss&1)][tt];
            const unsigned b = (ss >> 1) ? pw1[2*(ss&1)+1][tt] : pw0[2*(ss&1)+1][tt];
            int2v sw = __builtin_amdgcn_permlane32_swap((int)a, (int)b, false, false);
            pu.u[tt]     = (unsigned)sw[0];
            pu.u[2 + tt] = (unsigned)sw[1];
        }
        r.p[ss] = pu.s8;
    }
    return r;
}

__global__ __launch_bounds__(256)
void attn_mfma2(const unsigned short* __restrict__ Q, const unsigned short* __restrict__ Kg,
                const unsigned short* __restrict__ Vt, unsigned short* __restrict__ O)
{
    __shared__ __align__(16) unsigned short Ks[4][4096];
    __shared__ __align__(16) unsigned short Vs[4][4096];
    const int t = threadIdx.x, wid = t >> 6, lane = t & 63;
    const int l31 = lane & 31, h = lane >> 5;
    // grid (16, 32) = 512 blocks; swizzle: XCD c gets heads 4c..4c+3
    const int bid = blockIdx.y * 16 + blockIdx.x;
    const int swz = (bid & 7) * 64 + (bid >> 3);
    const int qt = swz & 15, bh = swz >> 4;
    const int b = bh >> 4, hh = bh & 15;
    const size_t qkbase = (size_t)b*SEQ*DIM + (size_t)hh*HDIM;
    const unsigned short* Qb = Q + qkbase;
    const unsigned short* Kb = Kg + qkbase;
    const unsigned short* Vb = Vt + (size_t)bh*HDIM*SEQ;
    unsigned short*       Ob = O + qkbase;
    const int q0 = qt*128 + wid*32;

    short8 qf[4];   // Q as B-operand: lane holds Q[q0+l31][ds*16 + h*8 + e]
    #pragma unroll
    for (int ds = 0; ds < 4; ++ds)
        qf[ds] = *(const short8*)&Qb[(size_t)(q0 + l31)*DIM + ds*16 + h*8];

    const int f0 = 2*wid, f1 = f0 + 1;
    const unsigned short* Kg0 = &Kb[(size_t)((f0>>2)*32 + l31)*DIM + (f0&3)*16 + h*8];
    const unsigned short* Kg1 = &Kb[(size_t)((f1>>2)*32 + l31)*DIM + (f1&3)*16 + h*8];
    const unsigned short* Vg0 = &Vb[(size_t)((f0>>2)*32 + l31)*SEQ + (f0&3)*16 + h*8];
    const unsigned short* Vg1 = &Vb[(size_t)((f1>>2)*32 + l31)*SEQ + (f1&3)*16 + h*8];

    auto stage = [&](int tn) {   // tn < 32 guaranteed by caller
        const size_t koK = (size_t)tn * 64 * DIM;
        const size_t koV = (size_t)tn * 64;
        const int bb = tn & 3;
        gld16(Kg0 + koK, &Ks[bb][f0*512]); gld16(Kg1 + koK, &Ks[bb][f1*512]);
        gld16(Vg0 + koV, &Vs[bb][f0*512]); gld16(Vg1 + koV, &Vs[bb][f1*512]);
    };

    f32x16 ctx0 = {}, ctx1 = {};
    float lsum = 0.0f;

    stage(0); stage(1);   // 8 loads in flight

    const int NW = SEQ/128;
    for (int w = 0; w < NW; ++w) {
        const int t0 = 2*w;
        const int ba = t0 & 3, bb2 = (t0+1) & 3;
        const bool more = (w + 1 < NW);

        // B1: own stage(t0) landed (4 newest stay in flight), then block-wide
        if (more) { asm volatile("s_waitcnt vmcnt(4)" ::: "memory"); }
        else      { asm volatile("s_waitcnt vmcnt(0)" ::: "memory"); }
        __builtin_amdgcn_s_barrier();
        if (more) stage(t0 + 2);

        // QK(t0)
        f32x16 s0a = {}, s1a = {};
        __builtin_amdgcn_s_setprio(1);
        #pragma unroll
        for (int ds = 0; ds < 4; ++ds) {
            short8 kf0 = *(const short8*)&Ks[ba][ds*512 + lane*8];
            short8 kf1 = *(const short8*)&Ks[ba][(4+ds)*512 + lane*8];
            s0a = mfma32(kf0, qf[ds], s0a);
            s1a = mfma32(kf1, qf[ds], s1a);
        }
        __builtin_amdgcn_s_setprio(0);

        PA pa = softmax_pack(s0a, s1a, lsum);

        // B2: own stage(t0+1) landed; frees nothing new for reads, gates stage(t0+3)
        if (more) { asm volatile("s_waitcnt vmcnt(4)" ::: "memory"); }
        else      { asm volatile("s_waitcnt vmcnt(0)" ::: "memory"); }
        __builtin_amdgcn_s_barrier();
        if (more) stage(t0 + 3);

        // QK(t1)
        f32x16 s0b = {}, s1b = {};
        __builtin_amdgcn_s_setprio(1);
        #pragma unroll
        for (int ds = 0; ds < 4; ++ds) {
            short8 kf0 = *(const short8*)&Ks[bb2][ds*512 + lane*8];
            short8 kf1 = *(const short8*)&Ks[bb2][(4+ds)*512 + lane*8];
            s0b = mfma32(kf0, qf[ds], s0b);
            s1b = mfma32(kf1, qf[ds], s1b);
        }
        // PV(t0) -- MFMA pipe busy while sm(t1) VALU runs after
        #pragma unroll
        for (int ss = 0; ss < 4; ++ss) {
            short8 vf0 = *(const short8*)&Vs[ba][ss*512 + lane*8];
            short8 vf1 = *(const short8*)&Vs[ba][(4+ss)*512 + lane*8];
            ctx0 = mfma32(pa.p[ss], vf0, ctx0);
            ctx1 = mfma32(pa.p[ss], vf1, ctx1);
        }
        __builtin_amdgcn_s_setprio(0);

        PA pb = softmax_pack(s0b, s1b, lsum);

        // PV(t1)
        __builtin_amdgcn_s_setprio(1);
        #pragma unroll
        for (int ss = 0; ss < 4; ++ss) {
            short8 vf0 = *(const short8*)&Vs[bb2][ss*512 + lane*8];
            short8 vf1 = *(const short8*)&Vs[bb2][(4+ss)*512 + lane*8];
            ctx0 = mfma32(pb.p[ss], vf0, ctx0);
            ctx1 = mfma32(pb.p[ss], vf1, ctx1);
        }
        __builtin_amdgcn_s_setprio(0);
    }

    const float linv = 1.0f / lsum;
    #pragma unroll
    for (int r = 0; r < 16; ++r) {
        const int qrow = (r&3) + 8*(r>>2) + 4*h;
        const float nm = __shfl(linv, qrow);
        unsigned short* p = &Ob[(size_t)(q0 + qrow)*DIM + l31];
        p[0]  = bf16rne(ctx0[r] * nm);
        p[32] = bf16rne(ctx1[r] * nm);
    }
}

extern "C" void kernel_launch(void* const* d_in, const int* in_sizes, int n_in,
                              void* d_out, int out_size, void* d_ws, size_t ws_size,
                              hipStream_t stream) {
    const float* x  = (const float*)d_in[0];
    const float* wq = (const float*)d_in[1];
    const float* bq = (const float*)d_in[2];
    const float* wk = (const float*)d_in[3];
    const float* bk = (const float*)d_in[4];
    const float* wv = (const float*)d_in[5];
    const float* bv = (const float*)d_in[6];
    const float* wo = (const float*)d_in[7];
    const float* bo = (const float*)d_in[8];
    float* out = (float*)d_out;

    // ws (ushort): Xb/Cb 4M | Wq 1M | Wk 1M | Wv 1M | Wo 1M | Qb 4M | Kb 4M | Vb 4M | Vtb 4M = 48 MB
    unsigned short* Xb  = (unsigned short*)d_ws;
    unsigned short* Wqb = Xb  + XN;
    unsigned short* Wkb = Wqb + WN;
    unsigned short* Wvb = Wkb + WN;
    unsigned short* Wob = Wvb + WN;
    unsigned short* Qb  = Wob + WN;
    unsigned short* Kb  = Qb  + XN;
    unsigned short* Vb  = Kb  + XN;
    unsigned short* Vtb = Vb  + XN;
    unsigned short* Cb  = Xb;   // attn output aliases Xb (x dead after QKV GEMM)

    prep<<<4096, 256, 0, stream>>>(x, wq, wk, wv, wo, Xb);

    gemm_qkv<<<dim3(24, 32), 256, 0, stream>>>(Xb, Wqb, Wkb, Wvb, bq, bk, bv, Qb, Kb, Vb);

    transpose_v<<<dim3(SEQ/64, BATCH*NHEADS), 256, 0, stream>>>(Vb, Vtb);
    attn_mfma2<<<dim3(SEQ/128, BATCH*NHEADS), 256, 0, stream>>>(Qb, Kb, Vtb, Cb);

    gemm_o<<<dim3(8, 64), 256, 0, stream>>>(Cb, Wob, bo, out);
}